// Round 1
// baseline (1980.951 us; speedup 1.0000x reference)
//
#include <hip/hip_runtime.h>

// ---------------------------------------------------------------------------
// SemanticMemoryLatentSpace: factored scan.
//   K_t = f_t (K_{t-1} + c_t e_t e_t^T)  =>  K_final = g*K0 + sum_s w_s e_s e_s^T
// Needed per step: tr_t = G[t,t], q_t = g*u_t + sum_{s<t} w_s G[s,t]^2,
// running ||K||^2 via n2 <- n2 + 2 c q + c^2 tr^2, clip f = min(1, 50/sqrt(n2)).
// Cluster/novelty scan kept explicit with centroids in LDS.
// Output: refined = g*(E K0) + (G .* w) E.
// ---------------------------------------------------------------------------

#define ALPHA_D 0.008164965809277261   // 0.02*sqrt(64/384)
#define A_BOOST 0.012247448713915891   // 1.5*ALPHA

// ---------------- generic 32x32-tile fp32 GEMMs (all dims multiples of 32) --
__global__ __launch_bounds__(256) void gemm_nt(const float* __restrict__ A,
                                               const float* __restrict__ B,
                                               float* __restrict__ C,
                                               int N, int K) {
  // C[i][j] = sum_k A[i*K+k] * B[j*K+k]
  __shared__ float As[32][33];
  __shared__ float Bs[32][33];
  int bx = blockIdx.x, by = blockIdx.y;
  int tid = threadIdx.x;
  int tx = tid & 15, ty = tid >> 4;
  float a00 = 0.f, a01 = 0.f, a10 = 0.f, a11 = 0.f;
  for (int k0 = 0; k0 < K; k0 += 32) {
    for (int l = tid; l < 1024; l += 256) {
      int r = l >> 5, c = l & 31;
      As[r][c] = A[(by * 32 + r) * K + k0 + c];
      Bs[r][c] = B[(bx * 32 + r) * K + k0 + c];
    }
    __syncthreads();
#pragma unroll
    for (int k = 0; k < 32; ++k) {
      float x0 = As[2 * ty][k], x1 = As[2 * ty + 1][k];
      float y0 = Bs[2 * tx][k], y1 = Bs[2 * tx + 1][k];
      a00 += x0 * y0; a01 += x0 * y1; a10 += x1 * y0; a11 += x1 * y1;
    }
    __syncthreads();
  }
  int i = by * 32 + 2 * ty, jj = bx * 32 + 2 * tx;
  C[i * N + jj] = a00;           C[i * N + jj + 1] = a01;
  C[(i + 1) * N + jj] = a10;     C[(i + 1) * N + jj + 1] = a11;
}

__global__ __launch_bounds__(256) void gemm_nn(const float* __restrict__ A,
                                               const float* __restrict__ B,
                                               float* __restrict__ C,
                                               int N, int K) {
  // C[i][j] = sum_k A[i*K+k] * B[k*N+j]
  __shared__ float As[32][33];
  __shared__ float Bs[32][33];
  int bx = blockIdx.x, by = blockIdx.y;
  int tid = threadIdx.x;
  int tx = tid & 15, ty = tid >> 4;
  float a00 = 0.f, a01 = 0.f, a10 = 0.f, a11 = 0.f;
  for (int k0 = 0; k0 < K; k0 += 32) {
    for (int l = tid; l < 1024; l += 256) {
      int r = l >> 5, c = l & 31;
      As[r][c] = A[(by * 32 + r) * K + k0 + c];
      Bs[r][c] = B[(k0 + r) * N + bx * 32 + c];
    }
    __syncthreads();
#pragma unroll
    for (int k = 0; k < 32; ++k) {
      float x0 = As[2 * ty][k], x1 = As[2 * ty + 1][k];
      float y0 = Bs[k][2 * tx], y1 = Bs[k][2 * tx + 1];
      a00 += x0 * y0; a01 += x0 * y1; a10 += x1 * y0; a11 += x1 * y1;
    }
    __syncthreads();
  }
  int i = by * 32 + 2 * ty, jj = bx * 32 + 2 * tx;
  C[i * N + jj] = a00;           C[i * N + jj + 1] = a01;
  C[(i + 1) * N + jj] = a10;     C[(i + 1) * N + jj + 1] = a11;
}

// out[i][j] = g*M0[i][j] + sum_s G[i][s]*W[s]*E[s][j]   (M=512,N=384,K=512)
__global__ __launch_bounds__(256) void final_gemm(const float* __restrict__ G,
                                                  const float* __restrict__ E,
                                                  const float* __restrict__ M0,
                                                  const float* __restrict__ W,
                                                  const float* __restrict__ gS,
                                                  float* __restrict__ out) {
  __shared__ float As[32][33];
  __shared__ float Bs[32][33];
  int bx = blockIdx.x, by = blockIdx.y;
  int tid = threadIdx.x;
  int tx = tid & 15, ty = tid >> 4;
  float a00 = 0.f, a01 = 0.f, a10 = 0.f, a11 = 0.f;
  for (int k0 = 0; k0 < 512; k0 += 32) {
    for (int l = tid; l < 1024; l += 256) {
      int r = l >> 5, c = l & 31;
      As[r][c] = G[(by * 32 + r) * 512 + k0 + c] * W[k0 + c];
      Bs[r][c] = E[(k0 + r) * 384 + bx * 32 + c];
    }
    __syncthreads();
#pragma unroll
    for (int k = 0; k < 32; ++k) {
      float x0 = As[2 * ty][k], x1 = As[2 * ty + 1][k];
      float y0 = Bs[k][2 * tx], y1 = Bs[k][2 * tx + 1];
      a00 += x0 * y0; a01 += x0 * y1; a10 += x1 * y0; a11 += x1 * y1;
    }
    __syncthreads();
  }
  float gv = gS[0];
  int i = by * 32 + 2 * ty, jj = bx * 32 + 2 * tx;
  out[i * 384 + jj]         = gv * M0[i * 384 + jj]         + a00;
  out[i * 384 + jj + 1]     = gv * M0[i * 384 + jj + 1]     + a01;
  out[(i + 1) * 384 + jj]     = gv * M0[(i + 1) * 384 + jj]     + a10;
  out[(i + 1) * 384 + jj + 1] = gv * M0[(i + 1) * 384 + jj + 1] + a11;
}

// ---------------- the sequential scan: one workgroup, 512 threads ----------
__global__ __launch_bounds__(512) void scan_kernel(const float* __restrict__ E,
                                                   const float* __restrict__ K0,
                                                   const float* __restrict__ G,
                                                   const float* __restrict__ M0,
                                                   float* __restrict__ Wout,
                                                   float* __restrict__ gOut) {
  // Centroids row-padded to 97 float4 (=388 words): spreads ds_read_b128
  // addresses across all 8 4-bank classes (stride 388 mod 32 == 4).
  __shared__ float4 Csh[100 * 97];   // 155200 B
  __shared__ float4 e_sh[96];        // 1536 B
  __shared__ float  u_sh[512];       // 2048 B
  __shared__ float  sims[128];
  __shared__ float  cn2[128];
  __shared__ double red[8];
  __shared__ double b_coeff, b_f;
  __shared__ int b_idx, b_create, b_nact;

  const int tid = threadIdx.x;
  const int lane = tid & 63, wv = tid >> 6;

  // ---- init: cn2, u_t = e_t^T K0 e_t, n2 = ||K0||_F^2 ----
  if (tid < 128) cn2[tid] = 0.f;
  for (int row = wv; row < 512; row += 8) {
    float p = 0.f;
#pragma unroll
    for (int i = 0; i < 6; ++i) {
      int d = lane + 64 * i;
      p += M0[row * 384 + d] * E[row * 384 + d];
    }
#pragma unroll
    for (int off = 32; off; off >>= 1) p += __shfl_down(p, off);
    if (lane == 0) u_sh[row] = p;
  }
  double kp = 0.0;
  for (int i = tid; i < 384 * 384; i += 512) {
    double v = (double)K0[i];
    kp += v * v;
  }
#pragma unroll
  for (int off = 32; off; off >>= 1) kp += __shfl_down(kp, off);
  if (lane == 0) red[wv] = kp;
  __syncthreads();

  double n2 = 0.0, g = 1.0, prevn = 0.0;
  int count = 0, activeCnt = 0;
  double coeff_c = 0.0, tr_c = 0.0;
  int create_c = 0;
  if (tid == 0) {
    for (int i = 0; i < 8; ++i) n2 += red[i];
    b_nact = 0;
  }
  double w_reg = 0.0;  // thread s owns w_s
  __syncthreads();

  const int j = tid >> 2, part = tid & 3;

  for (int t = 0; t < 512; ++t) {
    const int nact = b_nact;
    if (tid < 96) e_sh[tid] = ((const float4*)E)[t * 96 + tid];
    if (part == 0 && j >= nact) sims[j] = -2.0f;
    __syncthreads();  // S1: e_sh + inactive sims ready

    // cosine sims vs active centroids (4 threads per cluster, interleaved)
    if (j < nact) {
      const float4* crow = Csh + j * 97;
      float p = 0.f;
#pragma unroll
      for (int i = 0; i < 24; ++i) {
        float4 c4 = crow[part + 4 * i];
        float4 e4 = e_sh[part + 4 * i];
        p += c4.x * e4.x + c4.y * e4.y + c4.z * e4.z + c4.w * e4.w;
      }
      p += __shfl_down(p, 2);
      p += __shfl_down(p, 1);
      if (part == 0) {
        float enorm = sqrtf(G[t * 512 + t]);
        sims[j] = p / (sqrtf(cn2[j]) * enorm + 1e-8f);
      }
    }
    __syncthreads();  // S2: sims ready

    if (tid < 64) {
      // first-occurrence argmax over 128 slots (inactive = -2)
      float v = sims[tid];
      int vi = tid;
      float v2 = sims[tid + 64];
      if (v2 > v) { v = v2; vi = tid + 64; }
#pragma unroll
      for (int off = 32; off; off >>= 1) {
        float ov = __shfl_down(v, off);
        int oi = __shfl_down(vi, off);
        if (ov > v || (ov == v && oi < vi)) { v = ov; vi = oi; }
      }
      if (tid == 0) {
        double novelty = (activeCnt == 0) ? 1.0 : 1.0 - (double)v * (double)v;
        novelty = fmin(1.0, fmax(0.0, novelty));
        double nb = sqrt(n2);
        double growth = (count > 0 && prevn > 0.0)
                            ? (nb - prevn) / fmax(prevn, 1e-12)
                            : 0.0;
        double a = (growth < 0.01) ? A_BOOST : ALPHA_D;
        double iw = novelty * sqrt(novelty);
        double tr = (double)G[t * 512 + t];
        double pscale = (tr > 1e-8) ? (384.0 / fmax(tr, 1e-8)) : 1.0;
        coeff_c = a * iw * pscale;
        tr_c = tr;
        create_c = (novelty > 0.7 && activeCnt < 100) ? 1 : 0;
        b_coeff = coeff_c;
        b_create = create_c;
        b_idx = create_c ? activeCnt : vi;
      }
    }
    __syncthreads();  // S3: decisions broadcast

    // q_t = g*u_t + sum_{s<t} w_s * G[t,s]^2   (thread s holds w_s)
    double qp = 0.0;
    if (tid < t) {
      double gv = (double)G[t * 512 + tid];
      qp = w_reg * gv * gv;
    }
#pragma unroll
    for (int off = 32; off; off >>= 1) qp += __shfl_down(qp, off);
    if (lane == 0) red[wv] = qp;
    __syncthreads();  // S4: q partials ready

    if (tid == 0) {
      double q = 0.0;
      for (int i = 0; i < 8; ++i) q += red[i];
      q = g * (double)u_sh[t] + q;
      double n2n = n2 + 2.0 * coeff_c * q + coeff_c * coeff_c * tr_c * tr_c;
      double kn = sqrt(n2n);
      double f = (kn > 50.0) ? (50.0 / kn) : 1.0;
      n2 = n2n * f * f;
      prevn = sqrt(n2);
      g *= f;
      count++;
      if (create_c) activeCnt++;
      b_f = f;
      b_nact = activeCnt;
    }
    __syncthreads();  // S5: f broadcast

    {
      const double f = b_f;
      const int idx = b_idx, create = b_create;
      if (tid == t) w_reg = b_coeff;
      w_reg *= f;  // threads > t hold 0, harmless
      float pc = 0.f;
      if (tid < 96) {
        float4 o = Csh[idx * 97 + tid];
        float4 e4 = e_sh[tid];
        float4 nw;
        if (create) {
          nw = e4;
        } else {
          nw.x = 0.95f * o.x + 0.05f * e4.x;
          nw.y = 0.95f * o.y + 0.05f * e4.y;
          nw.z = 0.95f * o.z + 0.05f * e4.z;
          nw.w = 0.95f * o.w + 0.05f * e4.w;
        }
        Csh[idx * 97 + tid] = nw;
        pc = nw.x * nw.x + nw.y * nw.y + nw.z * nw.z + nw.w * nw.w;
      }
#pragma unroll
      for (int off = 32; off; off >>= 1) pc += __shfl_down(pc, off);
      if (lane == 0) red[wv] = (double)pc;
    }
    __syncthreads();  // S6: centroid norm partials ready

    if (tid == 0) {
      double s = 0.0;
      for (int i = 0; i < 8; ++i) s += red[i];
      cn2[b_idx] = (float)s;  // next read is after next iter's S1
    }
  }

  Wout[tid] = (float)w_reg;
  if (tid == 0) gOut[0] = (float)g;
}

extern "C" void kernel_launch(void* const* d_in, const int* in_sizes, int n_in,
                              void* d_out, int out_size, void* d_ws,
                              size_t ws_size, hipStream_t stream) {
  const float* E = (const float*)d_in[0];   // [512,384]
  const float* K0 = (const float*)d_in[1];  // [384,384]
  float* out = (float*)d_out;               // [512,384]

  float* G = (float*)d_ws;           // 512*512
  float* M0 = G + 512 * 512;         // 512*384
  float* W = M0 + 512 * 384;         // 512
  float* gS = W + 512;               // 1

  gemm_nt<<<dim3(16, 16), 256, 0, stream>>>(E, E, G, 512, 384);       // G = E E^T
  gemm_nn<<<dim3(12, 16), 256, 0, stream>>>(E, K0, M0, 384, 384);     // M0 = E K0
  scan_kernel<<<1, 512, 0, stream>>>(E, K0, G, M0, W, gS);
  final_gemm<<<dim3(12, 16), 256, 0, stream>>>(G, E, M0, W, gS, out);
}

// Round 2
// 1054.913 us; speedup vs baseline: 1.8778x; 1.8778x over previous
//
#include <hip/hip_runtime.h>

// ---------------------------------------------------------------------------
// SemanticMemoryLatentSpace, fully factored:
//   K_final = g*K0 + sum_s w_s e_s e_s^T   (scalar recurrence for g, w)
//   centroids C_j = d_j * sum_{s in j} bhat_s e_s  -> sims via Gram matrix
//   ||C_j||^2 exact scalar recurrence.
// Scan runs on a SINGLE WAVE: no barriers, shuffle butterflies, LDS atomics
// for the segmented per-cluster sums, G-row prefetch one step ahead.
// ---------------------------------------------------------------------------

#define ALPHA_D 0.008164965809277261   // 0.02*sqrt(64/384)
#define A_BOOST 0.012247448713915891   // 1.5*ALPHA

// ---------------- generic 32x32-tile fp32 GEMMs -----------------------------
__global__ __launch_bounds__(256) void gemm_nt(const float* __restrict__ A,
                                               const float* __restrict__ B,
                                               float* __restrict__ C,
                                               int N, int K) {
  __shared__ float As[32][33];
  __shared__ float Bs[32][33];
  int bx = blockIdx.x, by = blockIdx.y;
  int tid = threadIdx.x;
  int tx = tid & 15, ty = tid >> 4;
  float a00 = 0.f, a01 = 0.f, a10 = 0.f, a11 = 0.f;
  for (int k0 = 0; k0 < K; k0 += 32) {
    for (int l = tid; l < 1024; l += 256) {
      int r = l >> 5, c = l & 31;
      As[r][c] = A[(by * 32 + r) * K + k0 + c];
      Bs[r][c] = B[(bx * 32 + r) * K + k0 + c];
    }
    __syncthreads();
#pragma unroll
    for (int k = 0; k < 32; ++k) {
      float x0 = As[2 * ty][k], x1 = As[2 * ty + 1][k];
      float y0 = Bs[2 * tx][k], y1 = Bs[2 * tx + 1][k];
      a00 += x0 * y0; a01 += x0 * y1; a10 += x1 * y0; a11 += x1 * y1;
    }
    __syncthreads();
  }
  int i = by * 32 + 2 * ty, jj = bx * 32 + 2 * tx;
  C[i * N + jj] = a00;           C[i * N + jj + 1] = a01;
  C[(i + 1) * N + jj] = a10;     C[(i + 1) * N + jj + 1] = a11;
}

__global__ __launch_bounds__(256) void gemm_nn(const float* __restrict__ A,
                                               const float* __restrict__ B,
                                               float* __restrict__ C,
                                               int N, int K) {
  __shared__ float As[32][33];
  __shared__ float Bs[32][33];
  int bx = blockIdx.x, by = blockIdx.y;
  int tid = threadIdx.x;
  int tx = tid & 15, ty = tid >> 4;
  float a00 = 0.f, a01 = 0.f, a10 = 0.f, a11 = 0.f;
  for (int k0 = 0; k0 < K; k0 += 32) {
    for (int l = tid; l < 1024; l += 256) {
      int r = l >> 5, c = l & 31;
      As[r][c] = A[(by * 32 + r) * K + k0 + c];
      Bs[r][c] = B[(k0 + r) * N + bx * 32 + c];
    }
    __syncthreads();
#pragma unroll
    for (int k = 0; k < 32; ++k) {
      float x0 = As[2 * ty][k], x1 = As[2 * ty + 1][k];
      float y0 = Bs[k][2 * tx], y1 = Bs[k][2 * tx + 1];
      a00 += x0 * y0; a01 += x0 * y1; a10 += x1 * y0; a11 += x1 * y1;
    }
    __syncthreads();
  }
  int i = by * 32 + 2 * ty, jj = bx * 32 + 2 * tx;
  C[i * N + jj] = a00;           C[i * N + jj + 1] = a01;
  C[(i + 1) * N + jj] = a10;     C[(i + 1) * N + jj + 1] = a11;
}

// out[i][j] = g*M0[i][j] + sum_s G[i][s]*W[s]*E[s][j]
__global__ __launch_bounds__(256) void final_gemm(const float* __restrict__ G,
                                                  const float* __restrict__ E,
                                                  const float* __restrict__ M0,
                                                  const float* __restrict__ W,
                                                  const float* __restrict__ gS,
                                                  float* __restrict__ out) {
  __shared__ float As[32][33];
  __shared__ float Bs[32][33];
  int bx = blockIdx.x, by = blockIdx.y;
  int tid = threadIdx.x;
  int tx = tid & 15, ty = tid >> 4;
  float a00 = 0.f, a01 = 0.f, a10 = 0.f, a11 = 0.f;
  for (int k0 = 0; k0 < 512; k0 += 32) {
    for (int l = tid; l < 1024; l += 256) {
      int r = l >> 5, c = l & 31;
      As[r][c] = G[(by * 32 + r) * 512 + k0 + c] * W[k0 + c];
      Bs[r][c] = E[(k0 + r) * 384 + bx * 32 + c];
    }
    __syncthreads();
#pragma unroll
    for (int k = 0; k < 32; ++k) {
      float x0 = As[2 * ty][k], x1 = As[2 * ty + 1][k];
      float y0 = Bs[k][2 * tx], y1 = Bs[k][2 * tx + 1];
      a00 += x0 * y0; a01 += x0 * y1; a10 += x1 * y0; a11 += x1 * y1;
    }
    __syncthreads();
  }
  float gv = gS[0];
  int i = by * 32 + 2 * ty, jj = bx * 32 + 2 * tx;
  out[i * 384 + jj]         = gv * M0[i * 384 + jj]         + a00;
  out[i * 384 + jj + 1]     = gv * M0[i * 384 + jj + 1]     + a01;
  out[(i + 1) * 384 + jj]     = gv * M0[(i + 1) * 384 + jj]     + a10;
  out[(i + 1) * 384 + jj + 1] = gv * M0[(i + 1) * 384 + jj + 1] + a11;
}

// prep: blocks 0..127 -> u[row] = dot(M0[row], E[row]) (one wave per row)
//       blocks 128..191 -> ||K0||_F^2 partial sums, double atomicAdd
__global__ __launch_bounds__(256) void prep_kernel(const float* __restrict__ E,
                                                   const float* __restrict__ M0,
                                                   const float* __restrict__ K0,
                                                   float* __restrict__ u,
                                                   double* __restrict__ n2sum) {
  __shared__ double wr[4];
  int b = blockIdx.x;
  int tid = threadIdx.x, lane = tid & 63, wv = tid >> 6;
  if (b < 128) {
    int row = b * 4 + wv;
    const float4* e4 = (const float4*)(E + row * 384);
    const float4* m4 = (const float4*)(M0 + row * 384);
    float p = 0.f;
    for (int i = lane; i < 96; i += 64) {
      float4 a = e4[i], bb = m4[i];
      p += a.x * bb.x + a.y * bb.y + a.z * bb.z + a.w * bb.w;
    }
#pragma unroll
    for (int off = 32; off; off >>= 1) p += __shfl_down(p, off);
    if (lane == 0) u[row] = p;
  } else {
    int cb = b - 128;                       // 0..63
    const float* p = K0 + cb * 2304 + tid * 9;   // 64*256*9 = 147456 exactly
    double acc = 0.0;
#pragma unroll
    for (int i = 0; i < 9; ++i) { double v = (double)p[i]; acc += v * v; }
#pragma unroll
    for (int off = 32; off; off >>= 1) acc += __shfl_down(acc, off);
    if (lane == 0) wr[wv] = acc;
    __syncthreads();
    if (tid == 0) atomicAdd(n2sum, wr[0] + wr[1] + wr[2] + wr[3]);
  }
}

// ---------------- single-wave scan -----------------------------------------
__global__ __launch_bounds__(64) void scan_kernel(const float* __restrict__ G,
                                                  const float* __restrict__ u,
                                                  const double* __restrict__ n2sum,
                                                  float* __restrict__ Wout,
                                                  float* __restrict__ gOut) {
  __shared__ float raw[128];
  const int lane = threadIdx.x;

  // per-slot state: slot k of lane -> step s = 8*lane + k
  double what[8];
  float bhat[8];
  int aidx[8];
#pragma unroll
  for (int k = 0; k < 8; ++k) { what[k] = 0.0; bhat[k] = 0.f; aidx[k] = 0; }

  float4 ua = ((const float4*)u)[lane * 2];
  float4 ub = ((const float4*)u)[lane * 2 + 1];
  float u_own[8] = {ua.x, ua.y, ua.z, ua.w, ub.x, ub.y, ub.z, ub.w};

  // per-cluster state: clusters (lane) and (lane+64)
  float d0 = 1.f, d1 = 1.f, cn2_0 = 0.f, cn2_1 = 0.f;

  double n2 = n2sum[0];
  double g = 1.0, prevn = 0.0;
  int nact = 0, count = 0;

  raw[lane] = 0.f;
  raw[lane + 64] = 0.f;
  __builtin_amdgcn_sched_barrier(0);

  // prefetch row 0
  float4 gr0 = ((const float4*)G)[lane * 2];
  float4 gr1 = ((const float4*)G)[lane * 2 + 1];

  for (int t = 0; t < 512; ++t) {
    float ga[8] = {gr0.x, gr0.y, gr0.z, gr0.w, gr1.x, gr1.y, gr1.z, gr1.w};
    // prefetch next row (off critical path)
    int tn = (t + 1 < 512) ? t + 1 : 511;
    gr0 = ((const float4*)(G + tn * 512))[lane * 2];
    gr1 = ((const float4*)(G + tn * 512))[lane * 2 + 1];

    // segmented sums: raw[cluster] += bhat_s * G[s,t]  (only assigned s < t)
#pragma unroll
    for (int k = 0; k < 8; ++k) {
      int s = lane * 8 + k;
      if (s < t) atomicAdd(&raw[aidx[k]], bhat[k] * ga[k]);
    }
    __builtin_amdgcn_sched_barrier(0);

    // q partial: sum_s what_s * G[s,t]^2  (what=0 for unassigned slots)
    double qp = 0.0;
#pragma unroll
    for (int k = 0; k < 8; ++k) {
      double gv = (double)ga[k];
      qp += what[k] * gv * gv;
    }
#pragma unroll
    for (int off = 32; off; off >>= 1) qp += __shfl_xor(qp, off);

    // broadcast tr = G[t,t] and u_t from owning lane (t>>3), element (t&7)
    const int tk = t & 7, tl = t >> 3;
    float trsel = ga[0];
#pragma unroll
    for (int k = 1; k < 8; ++k) if (tk == k) trsel = ga[k];
    float tr = __shfl(trsel, tl);
    float usel = u_own[0];
#pragma unroll
    for (int k = 1; k < 8; ++k) if (tk == k) usel = u_own[k];
    float ut = __shfl(usel, tl);

    // sims for my clusters (reads forced after atomics by DS in-order + fence)
    float r0 = raw[lane], r1 = raw[lane + 64];
    __builtin_amdgcn_sched_barrier(0);
    float en = sqrtf(tr);
    float v0 = -2.f, v1 = -2.f;
    if (lane < nact)      v0 = d0 * r0 / (sqrtf(cn2_0) * en + 1e-8f);
    if (lane + 64 < nact) v1 = d1 * r1 / (sqrtf(cn2_1) * en + 1e-8f);
    float mv = v0; int mi = lane;
    if (v1 > mv) { mv = v1; mi = lane + 64; }
#pragma unroll
    for (int off = 32; off; off >>= 1) {
      float ov = __shfl_xor(mv, off);
      int oi = __shfl_xor(mi, off);
      if (ov > mv || (ov == mv && oi < mi)) { mv = ov; mi = oi; }
    }

    // scalar K-norm recurrence (all lanes redundantly, identical values)
    double novelty = (nact == 0) ? 1.0 : 1.0 - (double)mv * (double)mv;
    novelty = fmin(1.0, fmax(0.0, novelty));
    double nb = sqrt(n2);
    double growth = (count > 0 && prevn > 0.0)
                        ? (nb - prevn) / fmax(prevn, 1e-12) : 0.0;
    double a = (growth < 0.01) ? A_BOOST : ALPHA_D;
    double iw = novelty * sqrt(novelty);
    double trd = (double)tr;
    double c = a * iw * ((trd > 1e-8) ? 384.0 / fmax(trd, 1e-8) : 1.0);
    double q = g * ((double)ut + qp);
    double n2n = n2 + 2.0 * c * q + c * c * trd * trd;
    double kn = sqrt(n2n);
    double f = (kn > 50.0) ? 50.0 / kn : 1.0;
    double wh = c / g;          // w-hat_t = c_t / g_{t-1}
    n2 = n2n * f * f;
    prevn = sqrt(n2);
    g *= f;
    count++;

    int create = (novelty > 0.7 && nact < 100) ? 1 : 0;
    int idx = create ? nact : mi;
    nact += create;

    // cluster bookkeeping
    const int cl_lane = idx & 63, cl_hi = idx >> 6;
    float S_raw = raw[idx];                     // broadcast read (same addr)
    float dold = cl_hi ? d1 : d0;
    float cold = cl_hi ? cn2_1 : cn2_0;
    float dn_local = create ? 1.0f : 0.95f * dold;
    float cn_new = create ? tr
                          : (0.9025f * cold + 0.095f * (dold * S_raw) + 0.0025f * tr);
    if (lane == cl_lane) {
      if (cl_hi) { d1 = dn_local; cn2_1 = cn_new; }
      else       { d0 = dn_local; cn2_0 = cn_new; }
    }
    float d_bc = __shfl(dn_local, cl_lane);
    float bnew = create ? 1.0f : 0.05f / d_bc;

    // slot-t owner stores (static indices via unroll)
    if (lane == tl) {
#pragma unroll
      for (int k = 0; k < 8; ++k)
        if (k == tk) { bhat[k] = bnew; aidx[k] = idx; what[k] = wh; }
    }

    // reset accumulators for next step (after all reads of raw this step)
    raw[lane] = 0.f;
    raw[lane + 64] = 0.f;
    __builtin_amdgcn_sched_barrier(0);
  }

#pragma unroll
  for (int k = 0; k < 8; ++k) Wout[lane * 8 + k] = (float)(what[k] * g);
  if (lane == 0) gOut[0] = (float)g;
}

extern "C" void kernel_launch(void* const* d_in, const int* in_sizes, int n_in,
                              void* d_out, int out_size, void* d_ws,
                              size_t ws_size, hipStream_t stream) {
  const float* E = (const float*)d_in[0];   // [512,384]
  const float* K0 = (const float*)d_in[1];  // [384,384]
  float* out = (float*)d_out;               // [512,384]

  float* G = (float*)d_ws;                  // 512*512
  float* M0 = G + 512 * 512;                // 512*384
  float* W = M0 + 512 * 384;                // 512
  float* gS = W + 512;                      // 1
  float* u = gS + 1;                        // 512
  double* n2sum = (double*)((char*)d_ws + ((512 * 512 + 512 * 384 + 512 + 1 + 512 + 1) * 4 / 8 + 1) * 8);

  gemm_nt<<<dim3(16, 16), 256, 0, stream>>>(E, E, G, 512, 384);     // G = E E^T
  gemm_nn<<<dim3(12, 16), 256, 0, stream>>>(E, K0, M0, 384, 384);   // M0 = E K0
  hipMemsetAsync(n2sum, 0, sizeof(double), stream);
  prep_kernel<<<192, 256, 0, stream>>>(E, M0, K0, u, n2sum);
  scan_kernel<<<1, 64, 0, stream>>>(G, u, n2sum, W, gS);
  final_gemm<<<dim3(12, 16), 256, 0, stream>>>(G, E, M0, W, gS, out);
}

// Round 3
// 654.979 us; speedup vs baseline: 3.0244x; 1.6106x over previous
//
#include <hip/hip_runtime.h>

// ---------------------------------------------------------------------------
// SemanticMemoryLatentSpace, fully factored:
//   K_final = g*K0 + sum_s w_s e_s e_s^T   (scalar recurrence for g, w)
//   centroids C_j = d_j * sum_{s in j} bhat_s e_s  -> sims via Gram matrix
//   ||C_j||^2 exact scalar recurrence.
// Single-wave scan, no barriers. All cross-lane via VALU DPP + readlane
// (no ds_bpermute on the critical path). Scalar recurrence in fp32.
// ---------------------------------------------------------------------------

#define ALPHA_D 0.008164965809277261   // 0.02*sqrt(64/384)
#define A_BOOSTF 0.012247448713915891f // 1.5*ALPHA (growth==0 always => boosted)

// ---------------- cross-lane helpers (VALU only) ---------------------------
template <int CTRL>
__device__ __forceinline__ float dpp_f(float x) {
  return __int_as_float(
      __builtin_amdgcn_mov_dpp(__float_as_int(x), CTRL, 0xf, 0xf, true));
}
__device__ __forceinline__ float rdlane_f(float x, int l) {
  return __int_as_float(__builtin_amdgcn_readlane(__float_as_int(x), l));
}
// 64-lane sum -> uniform scalar. Stages: quad xor1, xor2, row_ror:4, row_ror:8,
// then combine the 4 row-sums via readlane.
__device__ __forceinline__ float wave_sum64(float v) {
  v += dpp_f<0xB1>(v);    // quad_perm [1,0,3,2]
  v += dpp_f<0x4E>(v);    // quad_perm [2,3,0,1]
  v += dpp_f<0x124>(v);   // row_ror:4
  v += dpp_f<0x128>(v);   // row_ror:8
  return (rdlane_f(v, 0) + rdlane_f(v, 16)) + (rdlane_f(v, 32) + rdlane_f(v, 48));
}
__device__ __forceinline__ float wave_max64(float v) {
  v = fmaxf(v, dpp_f<0xB1>(v));
  v = fmaxf(v, dpp_f<0x4E>(v));
  v = fmaxf(v, dpp_f<0x124>(v));
  v = fmaxf(v, dpp_f<0x128>(v));
  return fmaxf(fmaxf(rdlane_f(v, 0), rdlane_f(v, 16)),
               fmaxf(rdlane_f(v, 32), rdlane_f(v, 48)));
}

// ---------------- generic 32x32-tile fp32 GEMMs -----------------------------
__global__ __launch_bounds__(256) void gemm_nt(const float* __restrict__ A,
                                               const float* __restrict__ B,
                                               float* __restrict__ C,
                                               int N, int K) {
  __shared__ float As[32][33];
  __shared__ float Bs[32][33];
  int bx = blockIdx.x, by = blockIdx.y;
  int tid = threadIdx.x;
  int tx = tid & 15, ty = tid >> 4;
  float a00 = 0.f, a01 = 0.f, a10 = 0.f, a11 = 0.f;
  for (int k0 = 0; k0 < K; k0 += 32) {
    for (int l = tid; l < 1024; l += 256) {
      int r = l >> 5, c = l & 31;
      As[r][c] = A[(by * 32 + r) * K + k0 + c];
      Bs[r][c] = B[(bx * 32 + r) * K + k0 + c];
    }
    __syncthreads();
#pragma unroll
    for (int k = 0; k < 32; ++k) {
      float x0 = As[2 * ty][k], x1 = As[2 * ty + 1][k];
      float y0 = Bs[2 * tx][k], y1 = Bs[2 * tx + 1][k];
      a00 += x0 * y0; a01 += x0 * y1; a10 += x1 * y0; a11 += x1 * y1;
    }
    __syncthreads();
  }
  int i = by * 32 + 2 * ty, jj = bx * 32 + 2 * tx;
  C[i * N + jj] = a00;           C[i * N + jj + 1] = a01;
  C[(i + 1) * N + jj] = a10;     C[(i + 1) * N + jj + 1] = a11;
}

__global__ __launch_bounds__(256) void gemm_nn(const float* __restrict__ A,
                                               const float* __restrict__ B,
                                               float* __restrict__ C,
                                               int N, int K) {
  __shared__ float As[32][33];
  __shared__ float Bs[32][33];
  int bx = blockIdx.x, by = blockIdx.y;
  int tid = threadIdx.x;
  int tx = tid & 15, ty = tid >> 4;
  float a00 = 0.f, a01 = 0.f, a10 = 0.f, a11 = 0.f;
  for (int k0 = 0; k0 < K; k0 += 32) {
    for (int l = tid; l < 1024; l += 256) {
      int r = l >> 5, c = l & 31;
      As[r][c] = A[(by * 32 + r) * K + k0 + c];
      Bs[r][c] = B[(k0 + r) * N + bx * 32 + c];
    }
    __syncthreads();
#pragma unroll
    for (int k = 0; k < 32; ++k) {
      float x0 = As[2 * ty][k], x1 = As[2 * ty + 1][k];
      float y0 = Bs[k][2 * tx], y1 = Bs[k][2 * tx + 1];
      a00 += x0 * y0; a01 += x0 * y1; a10 += x1 * y0; a11 += x1 * y1;
    }
    __syncthreads();
  }
  int i = by * 32 + 2 * ty, jj = bx * 32 + 2 * tx;
  C[i * N + jj] = a00;           C[i * N + jj + 1] = a01;
  C[(i + 1) * N + jj] = a10;     C[(i + 1) * N + jj + 1] = a11;
}

// out[i][j] = g*M0[i][j] + sum_s G[i][s]*W[s]*E[s][j]
__global__ __launch_bounds__(256) void final_gemm(const float* __restrict__ G,
                                                  const float* __restrict__ E,
                                                  const float* __restrict__ M0,
                                                  const float* __restrict__ W,
                                                  const float* __restrict__ gS,
                                                  float* __restrict__ out) {
  __shared__ float As[32][33];
  __shared__ float Bs[32][33];
  int bx = blockIdx.x, by = blockIdx.y;
  int tid = threadIdx.x;
  int tx = tid & 15, ty = tid >> 4;
  float a00 = 0.f, a01 = 0.f, a10 = 0.f, a11 = 0.f;
  for (int k0 = 0; k0 < 512; k0 += 32) {
    for (int l = tid; l < 1024; l += 256) {
      int r = l >> 5, c = l & 31;
      As[r][c] = G[(by * 32 + r) * 512 + k0 + c] * W[k0 + c];
      Bs[r][c] = E[(k0 + r) * 384 + bx * 32 + c];
    }
    __syncthreads();
#pragma unroll
    for (int k = 0; k < 32; ++k) {
      float x0 = As[2 * ty][k], x1 = As[2 * ty + 1][k];
      float y0 = Bs[k][2 * tx], y1 = Bs[k][2 * tx + 1];
      a00 += x0 * y0; a01 += x0 * y1; a10 += x1 * y0; a11 += x1 * y1;
    }
    __syncthreads();
  }
  float gv = gS[0];
  int i = by * 32 + 2 * ty, jj = bx * 32 + 2 * tx;
  out[i * 384 + jj]         = gv * M0[i * 384 + jj]         + a00;
  out[i * 384 + jj + 1]     = gv * M0[i * 384 + jj + 1]     + a01;
  out[(i + 1) * 384 + jj]     = gv * M0[(i + 1) * 384 + jj]     + a10;
  out[(i + 1) * 384 + jj + 1] = gv * M0[(i + 1) * 384 + jj + 1] + a11;
}

// prep: blocks 0..127 -> u[row] = dot(M0[row], E[row]) (one wave per row)
//       blocks 128..191 -> Kpart[cb] = partial ||K0||_F^2 (deterministic)
__global__ __launch_bounds__(256) void prep_kernel(const float* __restrict__ E,
                                                   const float* __restrict__ M0,
                                                   const float* __restrict__ K0,
                                                   float* __restrict__ u,
                                                   float* __restrict__ Kpart) {
  __shared__ double wr[4];
  int b = blockIdx.x;
  int tid = threadIdx.x, lane = tid & 63, wv = tid >> 6;
  if (b < 128) {
    int row = b * 4 + wv;
    const float4* e4 = (const float4*)(E + row * 384);
    const float4* m4 = (const float4*)(M0 + row * 384);
    float p = 0.f;
    for (int i = lane; i < 96; i += 64) {
      float4 a = e4[i], bb = m4[i];
      p += a.x * bb.x + a.y * bb.y + a.z * bb.z + a.w * bb.w;
    }
#pragma unroll
    for (int off = 32; off; off >>= 1) p += __shfl_down(p, off);
    if (lane == 0) u[row] = p;
  } else {
    int cb = b - 128;                            // 0..63
    const float* p = K0 + cb * 2304 + tid * 9;   // 64*256*9 = 147456 exactly
    double acc = 0.0;
#pragma unroll
    for (int i = 0; i < 9; ++i) { double v = (double)p[i]; acc += v * v; }
#pragma unroll
    for (int off = 32; off; off >>= 1) acc += __shfl_down(acc, off);
    if (lane == 0) wr[wv] = acc;
    __syncthreads();
    if (tid == 0) Kpart[cb] = (float)(wr[0] + wr[1] + wr[2] + wr[3]);
  }
}

// ---------------- single-wave scan -----------------------------------------
__global__ __launch_bounds__(64) void scan_kernel(const float* __restrict__ G,
                                                  const float* __restrict__ u,
                                                  const float* __restrict__ Kpart,
                                                  float* __restrict__ Wout,
                                                  float* __restrict__ gOut) {
  __shared__ float raw[128];
  const int lane = threadIdx.x;

  // per-slot state: slot k of lane -> step s = 8*lane + k
  float what[8], bhat[8];
  int aidx[8];
#pragma unroll
  for (int k = 0; k < 8; ++k) { what[k] = 0.f; bhat[k] = 0.f; aidx[k] = 0; }

  float4 ua = ((const float4*)u)[lane * 2];
  float4 ub = ((const float4*)u)[lane * 2 + 1];
  float u_own[8] = {ua.x, ua.y, ua.z, ua.w, ub.x, ub.y, ub.z, ub.w};

  // per-cluster state: clusters (lane) and (lane+64)
  float d0 = 1.f, d1 = 1.f, cn2_0 = 0.f, cn2_1 = 0.f;

  float n2 = wave_sum64(Kpart[lane]);   // ||K0||_F^2, deterministic
  float g = 1.f, ginv = 1.f;
  int nact = 0;

  raw[lane] = 0.f;
  raw[lane + 64] = 0.f;
  __builtin_amdgcn_sched_barrier(0);

  // prefetch row 0
  float4 gr0 = ((const float4*)G)[lane * 2];
  float4 gr1 = ((const float4*)G)[lane * 2 + 1];

  for (int t = 0; t < 512; ++t) {
    float ga[8] = {gr0.x, gr0.y, gr0.z, gr0.w, gr1.x, gr1.y, gr1.z, gr1.w};
    // prefetch next row (off critical path)
    int tn = (t + 1 < 512) ? t + 1 : 511;
    gr0 = ((const float4*)(G + tn * 512))[lane * 2];
    gr1 = ((const float4*)(G + tn * 512))[lane * 2 + 1];

    // segmented sums: raw[cluster] += bhat_s * G[s,t]  (only assigned s < t)
#pragma unroll
    for (int k = 0; k < 8; ++k) {
      int s = lane * 8 + k;
      if (s < t) atomicAdd(&raw[aidx[k]], bhat[k] * ga[k]);
    }

    // q partial: sum_s what_s * G[s,t]^2 (what=0 for unassigned) — off-chain
    float qpl = 0.f;
#pragma unroll
    for (int k = 0; k < 8; ++k) qpl += what[k] * ga[k] * ga[k];
    float qp = wave_sum64(qpl);

    // broadcast tr = G[t,t], u_t from owner lane (uniform indices -> readlane)
    const int tk = t & 7, tl = t >> 3;
    float trsel = ga[0], usel = u_own[0];
#pragma unroll
    for (int k = 1; k < 8; ++k)
      if (tk == k) { trsel = ga[k]; usel = u_own[k]; }
    float tr = rdlane_f(trsel, tl);
    float ut = rdlane_f(usel, tl);

    // sims for my clusters (reads ordered after atomics by in-order DS pipe)
    float r0 = raw[lane];
    float r1 = raw[lane + 64];
    __builtin_amdgcn_sched_barrier(0);
    raw[lane] = 0.f;            // reset for next step (DS in-order after reads)
    raw[lane + 64] = 0.f;

    float en = sqrtf(tr);
    float v0 = (lane < nact)      ? d0 * r0 / (sqrtf(cn2_0) * en + 1e-8f) : -2.f;
    float v1 = (lane + 64 < nact) ? d1 * r1 / (sqrtf(cn2_1) * en + 1e-8f) : -2.f;
    float M = wave_max64(fmaxf(v0, v1));
    unsigned long long b0 = __ballot(v0 == M);
    unsigned long long b1 = __ballot(v1 == M);
    int idx_max = b0 ? (__ffsll(b0) - 1) : (64 + __ffsll(b1) - 1);

    // scalar recurrence (uniform, fp32). growth==0 always -> boosted alpha.
    float novelty = (nact == 0) ? 1.0f : 1.0f - M * M;
    novelty = fminf(1.0f, fmaxf(0.0f, novelty));
    float iw = novelty * sqrtf(novelty);
    float psc = (tr > 1e-8f) ? 384.0f / fmaxf(tr, 1e-8f) : 1.0f;
    float c = A_BOOSTF * iw * psc;
    float q = g * (ut + qp);
    float n2n = n2 + 2.0f * c * q + c * c * tr * tr;
    float kn = sqrtf(n2n);
    float f, finv;
    if (kn > 50.0f) { f = 50.0f / kn; finv = kn * 0.02f; }
    else            { f = 1.0f;       finv = 1.0f; }
    float wh = c * ginv;
    n2 = n2n * f * f;
    g *= f;
    ginv *= finv;

    int create = (novelty > 0.7f && nact < 100) ? 1 : 0;
    int idx = create ? nact : idx_max;
    nact += create;

    // cluster bookkeeping (idx uniform; force SGPR)
    const int idxs = __builtin_amdgcn_readfirstlane(idx);
    const int cl_lane = idxs & 63, cl_hi = idxs >> 6;
    float S_raw = rdlane_f(cl_hi ? r1 : r0, cl_lane);
    float dold = cl_hi ? d1 : d0;
    float cold = cl_hi ? cn2_1 : cn2_0;
    float dn_local = create ? 1.0f : 0.95f * dold;
    float cn_new = create ? tr
                          : (0.9025f * cold + 0.095f * (dold * S_raw) + 0.0025f * tr);
    if (lane == cl_lane) {
      if (cl_hi) { d1 = dn_local; cn2_1 = cn_new; }
      else       { d0 = dn_local; cn2_0 = cn_new; }
    }
    float d_bc = rdlane_f(dn_local, cl_lane);
    float bnew = create ? 1.0f : 0.05f / d_bc;

    // slot-t owner stores (static indices via unroll)
    if (lane == tl) {
#pragma unroll
      for (int k = 0; k < 8; ++k)
        if (k == tk) { bhat[k] = bnew; aidx[k] = idxs; what[k] = wh; }
    }
  }

#pragma unroll
  for (int k = 0; k < 8; ++k) Wout[lane * 8 + k] = what[k] * g;
  if (lane == 0) gOut[0] = g;
}

extern "C" void kernel_launch(void* const* d_in, const int* in_sizes, int n_in,
                              void* d_out, int out_size, void* d_ws,
                              size_t ws_size, hipStream_t stream) {
  const float* E = (const float*)d_in[0];   // [512,384]
  const float* K0 = (const float*)d_in[1];  // [384,384]
  float* out = (float*)d_out;               // [512,384]

  float* G = (float*)d_ws;                  // 512*512          (16B aligned)
  float* M0 = G + 512 * 512;                // 512*384          (16B aligned)
  float* u = M0 + 512 * 384;                // 512              (16B aligned)
  float* W = u + 512;                       // 512
  float* gS = W + 512;                      // 1
  float* Kpart = gS + 1;                    // 64

  gemm_nt<<<dim3(16, 16), 256, 0, stream>>>(E, E, G, 512, 384);     // G = E E^T
  gemm_nn<<<dim3(12, 16), 256, 0, stream>>>(E, K0, M0, 384, 384);   // M0 = E K0
  prep_kernel<<<192, 256, 0, stream>>>(E, M0, K0, u, Kpart);
  scan_kernel<<<1, 64, 0, stream>>>(G, u, Kpart, W, gS);
  final_gemm<<<dim3(12, 16), 256, 0, stream>>>(G, E, M0, W, gS, out);
}

// Round 4
// 461.581 us; speedup vs baseline: 4.2917x; 1.4190x over previous
//
#include <hip/hip_runtime.h>

// ---------------------------------------------------------------------------
// SemanticMemoryLatentSpace, fully factored:
//   K_final = g*K0 + sum_s w_s e_s e_s^T   (scalar recurrence for g, w)
//   centroids C_j = d_j * sum_{s in j} bhat_s e_s  -> sims via Gram matrix
// Single-wave scan, O(1) work per step:
//   RAW[j][c] = sum_{s in j} bhat_s G[s,c]  kept for current 128-col block
//   (one cluster row updated per step; rebuilt from an LDS journal at the
//    3 block boundaries), Q[c] = sum_s what_s G[s,c]^2 kept in registers.
// Cross-lane via DPP + readlane only; one max-reduce per step.
// ---------------------------------------------------------------------------

#define A_BOOSTF 0.012247448713915891f // 1.5*alpha (growth==0 always => boosted)

// ---------------- cross-lane helpers (VALU only) ---------------------------
template <int CTRL>
__device__ __forceinline__ float dpp_f(float x) {
  return __int_as_float(
      __builtin_amdgcn_mov_dpp(__float_as_int(x), CTRL, 0xf, 0xf, true));
}
__device__ __forceinline__ float rdlane_f(float x, int l) {
  return __int_as_float(__builtin_amdgcn_readlane(__float_as_int(x), l));
}
__device__ __forceinline__ float wave_sum64(float v) {
  v += dpp_f<0xB1>(v);    // quad_perm [1,0,3,2]
  v += dpp_f<0x4E>(v);    // quad_perm [2,3,0,1]
  v += dpp_f<0x124>(v);   // row_ror:4
  v += dpp_f<0x128>(v);   // row_ror:8
  return (rdlane_f(v, 0) + rdlane_f(v, 16)) + (rdlane_f(v, 32) + rdlane_f(v, 48));
}
__device__ __forceinline__ float wave_max64(float v) {
  v = fmaxf(v, dpp_f<0xB1>(v));
  v = fmaxf(v, dpp_f<0x4E>(v));
  v = fmaxf(v, dpp_f<0x124>(v));
  v = fmaxf(v, dpp_f<0x128>(v));
  return fmaxf(fmaxf(rdlane_f(v, 0), rdlane_f(v, 16)),
               fmaxf(rdlane_f(v, 32), rdlane_f(v, 48)));
}

// ---------------- generic 32x32-tile fp32 GEMMs -----------------------------
__global__ __launch_bounds__(256) void gemm_nt(const float* __restrict__ A,
                                               const float* __restrict__ B,
                                               float* __restrict__ C,
                                               int N, int K) {
  __shared__ float As[32][33];
  __shared__ float Bs[32][33];
  int bx = blockIdx.x, by = blockIdx.y;
  int tid = threadIdx.x;
  int tx = tid & 15, ty = tid >> 4;
  float a00 = 0.f, a01 = 0.f, a10 = 0.f, a11 = 0.f;
  for (int k0 = 0; k0 < K; k0 += 32) {
    for (int l = tid; l < 1024; l += 256) {
      int r = l >> 5, c = l & 31;
      As[r][c] = A[(by * 32 + r) * K + k0 + c];
      Bs[r][c] = B[(bx * 32 + r) * K + k0 + c];
    }
    __syncthreads();
#pragma unroll
    for (int k = 0; k < 32; ++k) {
      float x0 = As[2 * ty][k], x1 = As[2 * ty + 1][k];
      float y0 = Bs[2 * tx][k], y1 = Bs[2 * tx + 1][k];
      a00 += x0 * y0; a01 += x0 * y1; a10 += x1 * y0; a11 += x1 * y1;
    }
    __syncthreads();
  }
  int i = by * 32 + 2 * ty, jj = bx * 32 + 2 * tx;
  C[i * N + jj] = a00;           C[i * N + jj + 1] = a01;
  C[(i + 1) * N + jj] = a10;     C[(i + 1) * N + jj + 1] = a11;
}

__global__ __launch_bounds__(256) void gemm_nn(const float* __restrict__ A,
                                               const float* __restrict__ B,
                                               float* __restrict__ C,
                                               int N, int K) {
  __shared__ float As[32][33];
  __shared__ float Bs[32][33];
  int bx = blockIdx.x, by = blockIdx.y;
  int tid = threadIdx.x;
  int tx = tid & 15, ty = tid >> 4;
  float a00 = 0.f, a01 = 0.f, a10 = 0.f, a11 = 0.f;
  for (int k0 = 0; k0 < K; k0 += 32) {
    for (int l = tid; l < 1024; l += 256) {
      int r = l >> 5, c = l & 31;
      As[r][c] = A[(by * 32 + r) * K + k0 + c];
      Bs[r][c] = B[(k0 + r) * N + bx * 32 + c];
    }
    __syncthreads();
#pragma unroll
    for (int k = 0; k < 32; ++k) {
      float x0 = As[2 * ty][k], x1 = As[2 * ty + 1][k];
      float y0 = Bs[k][2 * tx], y1 = Bs[k][2 * tx + 1];
      a00 += x0 * y0; a01 += x0 * y1; a10 += x1 * y0; a11 += x1 * y1;
    }
    __syncthreads();
  }
  int i = by * 32 + 2 * ty, jj = bx * 32 + 2 * tx;
  C[i * N + jj] = a00;           C[i * N + jj + 1] = a01;
  C[(i + 1) * N + jj] = a10;     C[(i + 1) * N + jj + 1] = a11;
}

// out[i][j] = g*M0[i][j] + sum_s G[i][s]*W[s]*E[s][j]
__global__ __launch_bounds__(256) void final_gemm(const float* __restrict__ G,
                                                  const float* __restrict__ E,
                                                  const float* __restrict__ M0,
                                                  const float* __restrict__ W,
                                                  const float* __restrict__ gS,
                                                  float* __restrict__ out) {
  __shared__ float As[32][33];
  __shared__ float Bs[32][33];
  int bx = blockIdx.x, by = blockIdx.y;
  int tid = threadIdx.x;
  int tx = tid & 15, ty = tid >> 4;
  float a00 = 0.f, a01 = 0.f, a10 = 0.f, a11 = 0.f;
  for (int k0 = 0; k0 < 512; k0 += 32) {
    for (int l = tid; l < 1024; l += 256) {
      int r = l >> 5, c = l & 31;
      As[r][c] = G[(by * 32 + r) * 512 + k0 + c] * W[k0 + c];
      Bs[r][c] = E[(k0 + r) * 384 + bx * 32 + c];
    }
    __syncthreads();
#pragma unroll
    for (int k = 0; k < 32; ++k) {
      float x0 = As[2 * ty][k], x1 = As[2 * ty + 1][k];
      float y0 = Bs[k][2 * tx], y1 = Bs[k][2 * tx + 1];
      a00 += x0 * y0; a01 += x0 * y1; a10 += x1 * y0; a11 += x1 * y1;
    }
    __syncthreads();
  }
  float gv = gS[0];
  int i = by * 32 + 2 * ty, jj = bx * 32 + 2 * tx;
  out[i * 384 + jj]         = gv * M0[i * 384 + jj]         + a00;
  out[i * 384 + jj + 1]     = gv * M0[i * 384 + jj + 1]     + a01;
  out[(i + 1) * 384 + jj]     = gv * M0[(i + 1) * 384 + jj]     + a10;
  out[(i + 1) * 384 + jj + 1] = gv * M0[(i + 1) * 384 + jj + 1] + a11;
}

// prep: blocks 0..127 -> u[row] = dot(M0[row], E[row]) (one wave per row)
//       blocks 128..191 -> Kpart[cb] = partial ||K0||_F^2 (deterministic)
__global__ __launch_bounds__(256) void prep_kernel(const float* __restrict__ E,
                                                   const float* __restrict__ M0,
                                                   const float* __restrict__ K0,
                                                   float* __restrict__ u,
                                                   float* __restrict__ Kpart) {
  __shared__ double wr[4];
  int b = blockIdx.x;
  int tid = threadIdx.x, lane = tid & 63, wv = tid >> 6;
  if (b < 128) {
    int row = b * 4 + wv;
    const float4* e4 = (const float4*)(E + row * 384);
    const float4* m4 = (const float4*)(M0 + row * 384);
    float p = 0.f;
    for (int i = lane; i < 96; i += 64) {
      float4 a = e4[i], bb = m4[i];
      p += a.x * bb.x + a.y * bb.y + a.z * bb.z + a.w * bb.w;
    }
#pragma unroll
    for (int off = 32; off; off >>= 1) p += __shfl_down(p, off);
    if (lane == 0) u[row] = p;
  } else {
    int cb = b - 128;                            // 0..63
    const float* p = K0 + cb * 2304 + tid * 9;   // 64*256*9 = 147456 exactly
    double acc = 0.0;
#pragma unroll
    for (int i = 0; i < 9; ++i) { double v = (double)p[i]; acc += v * v; }
#pragma unroll
    for (int off = 32; off; off >>= 1) acc += __shfl_down(acc, off);
    if (lane == 0) wr[wv] = acc;
    __syncthreads();
    if (tid == 0) Kpart[cb] = (float)(wr[0] + wr[1] + wr[2] + wr[3]);
  }
}

// ---------------- single-wave scan -----------------------------------------
__global__ __launch_bounds__(64) void scan_kernel(const float* __restrict__ G,
                                                  const float* __restrict__ u,
                                                  const float* __restrict__ Kpart,
                                                  float* __restrict__ Wout,
                                                  float* __restrict__ gOut) {
  __shared__ float RAW[128 * 129];   // [cluster][col], pad 129 -> 2-way banks
  __shared__ float4 SLOT[512];       // journal: {bhat, what, idx, 0} per step

  const int lane = threadIdx.x;
  const int row_off0 = lane * 129;
  const int row_off1 = (lane + 64) * 129;

  float4 ua = ((const float4*)u)[lane * 2];
  float4 ub = ((const float4*)u)[lane * 2 + 1];
  float u_own[8] = {ua.x, ua.y, ua.z, ua.w, ub.x, ub.y, ub.z, ub.w};

  // per-cluster state: clusters (lane) and (lane+64)
  float d0 = 1.f, d1 = 1.f, cn2_0 = 0.f, cn2_1 = 0.f, cnr0 = 0.f, cnr1 = 0.f;

  float n2 = wave_sum64(Kpart[lane]);   // ||K0||_F^2, deterministic
  float g = 1.f, ginv = 1.f;
  float q0 = 0.f, q1 = 0.f;             // Q[lane], Q[lane+64] of current block
  int nact = 0;

  // zero RAW
  float4 z4 = {0.f, 0.f, 0.f, 0.f};
  for (int i = lane; i < 4128; i += 64) ((float4*)RAW)[i] = z4;
  __builtin_amdgcn_sched_barrier(0);

  // prefetch row 0 (block base 0): lane holds cols lane and lane+64
  float ga0 = G[lane];
  float ga1 = G[64 + lane];

  for (int t = 0; t < 512; ++t) {
    const int c = t & 127;
    if (t && c == 0) {
      // ---- block-boundary rebuild: RAW/Q for new block cols [t, t+128) ----
      for (int i = lane; i < 4128; i += 64) ((float4*)RAW)[i] = z4;
      q0 = 0.f; q1 = 0.f;
      __builtin_amdgcn_sched_barrier(0);
      const float* Gb = G + t;   // column base of new block
      for (int s = 0; s < t; s += 8) {
        float a0[8], a1[8];
        float4 sl[8];
#pragma unroll
        for (int j = 0; j < 8; ++j) {
          a0[j] = Gb[(s + j) * 512 + lane];
          a1[j] = Gb[(s + j) * 512 + 64 + lane];
          sl[j] = SLOT[s + j];
        }
#pragma unroll
        for (int j = 0; j < 8; ++j) {
          float bh = sl[j].x, wh = sl[j].y;
          int id = __float_as_int(sl[j].z);
          atomicAdd(&RAW[id * 129 + lane], bh * a0[j]);
          atomicAdd(&RAW[id * 129 + 64 + lane], bh * a1[j]);
          q0 += wh * a0[j] * a0[j];
          q1 += wh * a1[j] * a1[j];
        }
      }
      __builtin_amdgcn_sched_barrier(0);
    }

    // prefetch next row's block columns
    const int tn = (t + 1 < 512) ? t + 1 : 511;
    const int nbase = tn & ~127;
    float p0 = G[tn * 512 + nbase + lane];
    float p1 = G[tn * 512 + nbase + 64 + lane];

    // uniform broadcasts: tr = G[t,t], u_t, q_t
    float trsel = (c < 64) ? ga0 : ga1;
    float tr = rdlane_f(trsel, c & 63);
    const int tk = t & 7, tl = t >> 3;
    float usel = u_own[0];
#pragma unroll
    for (int k = 1; k < 8; ++k) if (tk == k) usel = u_own[k];
    float ut = rdlane_f(usel, tl);
    float qsel = (c < 64) ? q0 : q1;
    float qp = rdlane_f(qsel, c & 63);

    // sims: column c of RAW (2-way bank aliasing only)
    float r0 = RAW[row_off0 + c];
    float r1 = RAW[row_off1 + c];
    __builtin_amdgcn_sched_barrier(0);

    float en = __builtin_amdgcn_sqrtf(tr);
    float v0 = (lane < nact)
                   ? d0 * r0 * __builtin_amdgcn_rcpf(cnr0 * en + 1e-8f) : -2.f;
    float v1 = (lane + 64 < nact)
                   ? d1 * r1 * __builtin_amdgcn_rcpf(cnr1 * en + 1e-8f) : -2.f;
    float M = wave_max64(fmaxf(v0, v1));
    unsigned long long b0 = __ballot(v0 == M);
    unsigned long long b1 = __ballot(v1 == M);
    int idx_max = b0 ? (__ffsll(b0) - 1) : (64 + __ffsll(b1) - 1);

    // novelty / coefficient (uniform)
    float novelty = (nact == 0) ? 1.0f : 1.0f - M * M;
    novelty = fminf(1.0f, fmaxf(0.0f, novelty));
    float iw = novelty * __builtin_amdgcn_sqrtf(novelty);
    float psc = (tr > 1e-8f) ? 384.0f * __builtin_amdgcn_rcpf(fmaxf(tr, 1e-8f))
                             : 1.0f;
    float cc = A_BOOSTF * iw * psc;

    int create = (novelty > 0.7f && nact < 100) ? 1 : 0;
    int idx = create ? nact : idx_max;
    nact += create;
    const int idxs = __builtin_amdgcn_readfirstlane(idx);
    const int cl_lane = idxs & 63, cl_hi = idxs >> 6;

    // cluster bookkeeping
    float S_raw = rdlane_f(cl_hi ? r1 : r0, cl_lane);
    float dold = cl_hi ? d1 : d0;
    float cold = cl_hi ? cn2_1 : cn2_0;
    float dn_local = create ? 1.0f : 0.95f * dold;
    float cn_new = create ? tr
                          : (0.9025f * cold + 0.095f * (dold * S_raw) + 0.0025f * tr);
    float cnr_new = __builtin_amdgcn_sqrtf(cn_new);
    if (lane == cl_lane) {
      if (cl_hi) { d1 = dn_local; cn2_1 = cn_new; cnr1 = cnr_new; }
      else       { d0 = dn_local; cn2_0 = cn_new; cnr0 = cnr_new; }
    }
    float d_bc = rdlane_f(dn_local, cl_lane);
    float bnew = create ? 1.0f : 0.05f * __builtin_amdgcn_rcpf(d_bc);

    // RAW incremental update: row idxs, cols (lane) and (lane+64) of block
    atomicAdd(&RAW[idxs * 129 + lane], bnew * ga0);
    atomicAdd(&RAW[idxs * 129 + 64 + lane], bnew * ga1);
    __builtin_amdgcn_sched_barrier(0);

    // lagging n2/g chain (does not feed next step's decisions)
    float q = g * (ut + qp);
    float n2n = n2 + 2.0f * cc * q + cc * cc * tr * tr;
    float kn = __builtin_amdgcn_sqrtf(n2n);
    float f, finv;
    if (kn > 50.0f) { f = 50.0f * __builtin_amdgcn_rcpf(kn); finv = kn * 0.02f; }
    else            { f = 1.0f;                               finv = 1.0f; }
    float wh = cc * ginv;
    n2 = n2n * f * f;
    g *= f;
    ginv *= finv;

    // Q incremental update (after q read)
    q0 += wh * ga0 * ga0;
    q1 += wh * ga1 * ga1;

    // journal write (uniform values)
    if (lane == 0) {
      float4 rec = {bnew, wh, __int_as_float(idxs), 0.f};
      SLOT[t] = rec;
    }

    ga0 = p0;
    ga1 = p1;
  }

  for (int s = lane; s < 512; s += 64) Wout[s] = SLOT[s].y * g;
  if (lane == 0) gOut[0] = g;
}

extern "C" void kernel_launch(void* const* d_in, const int* in_sizes, int n_in,
                              void* d_out, int out_size, void* d_ws,
                              size_t ws_size, hipStream_t stream) {
  const float* E = (const float*)d_in[0];   // [512,384]
  const float* K0 = (const float*)d_in[1];  // [384,384]
  float* out = (float*)d_out;               // [512,384]

  float* G = (float*)d_ws;                  // 512*512
  float* M0 = G + 512 * 512;                // 512*384
  float* u = M0 + 512 * 384;                // 512
  float* W = u + 512;                       // 512
  float* gS = W + 512;                      // 1
  float* Kpart = gS + 1;                    // 64

  gemm_nt<<<dim3(16, 16), 256, 0, stream>>>(E, E, G, 512, 384);     // G = E E^T
  gemm_nn<<<dim3(12, 16), 256, 0, stream>>>(E, K0, M0, 384, 384);   // M0 = E K0
  prep_kernel<<<192, 256, 0, stream>>>(E, M0, K0, u, Kpart);
  scan_kernel<<<1, 64, 0, stream>>>(G, u, Kpart, W, gS);
  final_gemm<<<dim3(12, 16), 256, 0, stream>>>(G, E, M0, W, gS, out);
}